// Round 1
// baseline (654.942 us; speedup 1.0000x reference)
//
#include <hip/hip_runtime.h>
#include <cstdint>
#include <cstddef>

#define B_ 64
#define S_ 8
#define D_ 2048
#define V_ 128000
#define CAND_CAP 2048

// ---------------- threefry2x32 (JAX-compatible) ----------------
__device__ __forceinline__ uint32_t rotl32(uint32_t x, int r){ return (x << r) | (x >> (32 - r)); }
__device__ __forceinline__ void tfround(uint32_t& x0, uint32_t& x1, int r){
  x0 += x1; x1 = rotl32(x1, r); x1 ^= x0;
}
__device__ __forceinline__ void threefry2x32(uint32_t k0, uint32_t k1, uint32_t c0, uint32_t c1,
                                             uint32_t& o0, uint32_t& o1){
  uint32_t ks2 = k0 ^ k1 ^ 0x1BD11BDAu;
  uint32_t x0 = c0 + k0, x1 = c1 + k1;
  tfround(x0,x1,13); tfround(x0,x1,15); tfround(x0,x1,26); tfround(x0,x1,6);
  x0 += k1; x1 += ks2 + 1u;
  tfround(x0,x1,17); tfround(x0,x1,29); tfround(x0,x1,16); tfround(x0,x1,24);
  x0 += ks2; x1 += k0 + 2u;
  tfround(x0,x1,13); tfround(x0,x1,15); tfround(x0,x1,26); tfround(x0,x1,6);
  x0 += k0; x1 += k1 + 3u;
  tfround(x0,x1,17); tfround(x0,x1,29); tfround(x0,x1,16); tfround(x0,x1,24);
  x0 += k1; x1 += ks2 + 4u;
  tfround(x0,x1,13); tfround(x0,x1,15); tfround(x0,x1,26); tfround(x0,x1,6);
  x0 += ks2; x1 += k0 + 5u;
  o0 = x0; o1 = x1;
}

// JAX default (modern): threefry_partitionable=True -> bits = x0^x1 of counter (0, j).
// If tokens mismatch while logits pass, set to 0 (legacy split-halves scheme).
#define JAX_PARTITIONABLE 1

__device__ __forceinline__ float gumbel_at(uint32_t b, uint32_t v){
  uint32_t j = b * (uint32_t)V_ + v;
  uint32_t bits;
#if JAX_PARTITIONABLE
  uint32_t o0, o1; threefry2x32(0u, 42u, 0u, j, o0, o1);
  bits = o0 ^ o1;
#else
  const uint32_t HALF = 4096000u;  // B*V/2
  uint32_t o0, o1;
  if (j < HALF){ threefry2x32(0u, 42u, j, j + HALF, o0, o1); bits = o0; }
  else        { threefry2x32(0u, 42u, j - HALF, j, o0, o1); bits = o1; }
#endif
  uint32_t fb = (bits >> 9) | 0x3F800000u;
  float f = __uint_as_float(fb) - 1.0f;          // uniform in [0,1), multiples of 2^-23
  const float TINY = 1.17549435e-38f;
  float u = fmaxf(TINY, f + TINY);               // matches jax.random.uniform(minval=tiny, maxval=1)
  return -logf(-logf(u));
}

__device__ __forceinline__ unsigned ordkey(float f){
  unsigned u = __float_as_uint(f);
  return (u & 0x80000000u) ? ~u : (u | 0x80000000u);
}
__device__ __forceinline__ float ordinv(unsigned o){
  unsigned u = (o & 0x80000000u) ? (o & 0x7FFFFFFFu) : ~o;
  return __uint_as_float(u);
}

// ---------------- kernels ----------------

// gather h (transposed: hT[k][b]) + zero candidate counters
__global__ __launch_bounds__(256) void Sampler_gather(const float* __restrict__ x,
    const int* __restrict__ out_pos, float* __restrict__ hT, unsigned* __restrict__ cnt){
  const int pos = out_pos[0];
  int i = blockIdx.x * 256 + threadIdx.x;
  if (i < B_ * D_){
    int kq = i >> 6;   // k
    int bq = i & 63;   // b
    hT[i] = x[((size_t)bq * S_ + pos) * D_ + kq];
  }
  if (i < 64) cnt[i] = 0;
}

// fp32 GEMM: out[b][v] = sum_k hT[k][b]*emb[v][k] + bias[v]
// tile 64(M) x 256(N), BK=32, 256 threads, 8x8 micro-tile
__global__ __launch_bounds__(256) void Sampler_gemm(
    const float* __restrict__ hT,   // [D_][64]
    const float* __restrict__ emb,  // [V_][D_]
    const float* __restrict__ bias, // [V_]
    float* __restrict__ out)        // [64][V_]
{
  __shared__ float hs[32][68];      // stride 68 floats = 272B (16B aligned rows)
  __shared__ float es[32 * 388];    // swizzled: phys col p(v)=v+4*(v>>3), stride 388 (1552B)
  const int tid = threadIdx.x;
  const int ty = tid >> 5;          // 0..7  -> rows 8*ty..8*ty+7
  const int tx = tid & 31;          // 0..31 -> cols 8*tx..8*tx+7
  const int v0 = blockIdx.x << 8;   // *256

  float acc[8][8];
#pragma unroll
  for (int i = 0; i < 8; ++i)
#pragma unroll
    for (int j = 0; j < 8; ++j) acc[i][j] = 0.f;

  for (int k0 = 0; k0 < D_; k0 += 32){
    // stage hT tile: 32 k-rows x 64 b
#pragma unroll
    for (int r = 0; r < 2; ++r){
      int flat = r * 256 + tid;          // 0..511
      int row  = flat >> 4;              // 0..31
      int c4   = (flat & 15) << 2;       // 0..60
      float4 a = *(const float4*)&hT[(size_t)(k0 + row) * 64 + c4];
      *(float4*)&hs[row][c4] = a;
    }
    // stage emb tile transposed+swizzled: 256 v x 32 k
#pragma unroll
    for (int r = 0; r < 8; ++r){
      int flat = r * 256 + tid;          // 0..2047
      int v    = flat >> 3;              // 0..255
      int kc   = (flat & 7) << 2;        // 0,4,...,28
      float4 e = *(const float4*)&emb[(size_t)(v0 + v) * D_ + k0 + kc];
      int pv = v + ((v >> 3) << 2);      // v + 4*(v/8)
      es[(kc + 0) * 388 + pv] = e.x;
      es[(kc + 1) * 388 + pv] = e.y;
      es[(kc + 2) * 388 + pv] = e.z;
      es[(kc + 3) * 388 + pv] = e.w;
    }
    __syncthreads();
#pragma unroll 4
    for (int k = 0; k < 32; ++k){
      float4 a0 = *(const float4*)&hs[k][ty << 3];
      float4 a1 = *(const float4*)&hs[k][(ty << 3) + 4];
      const float* ep = &es[k * 388 + 12 * tx];  // p(8tx)=12tx, contiguous 8 floats
      float4 b0 = *(const float4*)ep;
      float4 b1 = *(const float4*)(ep + 4);
      float a[8] = {a0.x, a0.y, a0.z, a0.w, a1.x, a1.y, a1.z, a1.w};
      float bb[8] = {b0.x, b0.y, b0.z, b0.w, b1.x, b1.y, b1.z, b1.w};
#pragma unroll
      for (int i = 0; i < 8; ++i)
#pragma unroll
        for (int j = 0; j < 8; ++j)
          acc[i][j] = fmaf(a[i], bb[j], acc[i][j]);
    }
    __syncthreads();
  }
  // epilogue: + bias, vectorized stores
#pragma unroll
  for (int i = 0; i < 8; ++i){
    const int bq = (ty << 3) + i;
    float* op = out + (size_t)bq * V_ + v0 + (tx << 3);
    const float* bp = bias + v0 + (tx << 3);
    float4 o0, o1;
    o0.x = acc[i][0] + bp[0]; o0.y = acc[i][1] + bp[1];
    o0.z = acc[i][2] + bp[2]; o0.w = acc[i][3] + bp[3];
    o1.x = acc[i][4] + bp[4]; o1.y = acc[i][5] + bp[5];
    o1.z = acc[i][6] + bp[6]; o1.w = acc[i][7] + bp[7];
    *(float4*)op = o0;
    *(float4*)(op + 4) = o1;
  }
}

// per-row max, softmax denom Z, and 64-bin histogram of (M - l) with bin width 0.125
__global__ __launch_bounds__(1024) void Sampler_rowstats(const float* __restrict__ logits,
    float* __restrict__ Mb, float* __restrict__ Zb, unsigned* __restrict__ hist){
  __shared__ float red[16];
  __shared__ float sM;
  __shared__ unsigned wh[16][64];
  const int b = blockIdx.x;
  const int tid = threadIdx.x;
  const int lane = tid & 63, wid = tid >> 6;
  const float* row = logits + (size_t)b * V_;

  float m = -3.4e38f;
  for (int i = tid; i < V_; i += 1024) m = fmaxf(m, row[i]);
#pragma unroll
  for (int off = 32; off; off >>= 1) m = fmaxf(m, __shfl_down(m, off));
  if (lane == 0) red[wid] = m;
  __syncthreads();
  if (tid == 0){
    float mm = red[0];
    for (int i = 1; i < 16; ++i) mm = fmaxf(mm, red[i]);
    sM = mm;
  }
  for (int i = tid; i < 16 * 64; i += 1024) ((unsigned*)wh)[i] = 0;
  __syncthreads();

  const float M = sM;
  float z = 0.f;
  for (int i = tid; i < V_; i += 1024){
    float l = row[i];
    z += expf(l - M);
    int bin = (int)((M - l) * 8.0f);
    bin = bin > 63 ? 63 : bin;
    atomicAdd(&wh[wid][bin], 1u);
  }
#pragma unroll
  for (int off = 32; off; off >>= 1) z += __shfl_down(z, off);
  __syncthreads();
  if (lane == 0) red[wid] = z;
  __syncthreads();
  if (tid == 0){
    float zz = 0.f;
    for (int i = 0; i < 16; ++i) zz += red[i];
    Zb[b] = zz; Mb[b] = M;
  }
  if (tid < 64){
    unsigned s = 0;
#pragma unroll
    for (int w = 0; w < 16; ++w) s += wh[w][tid];
    hist[b * 64 + tid] = s;
  }
}

// pick per-row collection threshold: smallest bin with cumulative count >= 128 (>= K_max=63)
__global__ __launch_bounds__(64) void Sampler_thresh(const unsigned* __restrict__ hist,
    const float* __restrict__ Mb, float* __restrict__ Tb){
  const int b = threadIdx.x;
  unsigned cum = 0; int chosen = 63;
  for (int i = 0; i < 64; ++i){
    cum += hist[b * 64 + i];
    if (cum >= 128u){ chosen = i; break; }
  }
  Tb[b] = Mb[b] - 0.125f * (float)(chosen + 1);
}

// collect candidates l > T
__global__ __launch_bounds__(1024) void Sampler_collect(const float* __restrict__ logits,
    const float* __restrict__ Tb, unsigned* __restrict__ cnt,
    float* __restrict__ cval, unsigned* __restrict__ cidx){
  const int b = blockIdx.x;
  const float T = Tb[b];
  const float* row = logits + (size_t)b * V_;
  for (int i = threadIdx.x; i < V_; i += 1024){
    float l = row[i];
    if (l > T){
      unsigned pz = atomicAdd(&cnt[b], 1u);
      if (pz < CAND_CAP){ cval[b * CAND_CAP + pz] = l; cidx[b * CAND_CAP + pz] = (unsigned)i; }
    }
  }
}

// extract top-K (stable: value desc, index asc) by iterative argmax over candidates
__global__ __launch_bounds__(256) void Sampler_topk(const unsigned* __restrict__ cnt,
    const float* __restrict__ cval, const unsigned* __restrict__ cidx,
    const int* __restrict__ top_ks, float* __restrict__ tv, unsigned* __restrict__ ti,
    unsigned* __restrict__ kef){
  __shared__ unsigned long long keys[CAND_CAP];
  __shared__ unsigned long long red[4];
  const int b = blockIdx.x;
  const int tid = threadIdx.x;
  int n = (int)min(cnt[b], (unsigned)CAND_CAP);
  for (int i = tid; i < CAND_CAP; i += 256){
    unsigned long long kk = 0ull;
    if (i < n){
      unsigned o = ordkey(cval[b * CAND_CAP + i]);
      kk = ((unsigned long long)o << 32) | (unsigned long long)(0xFFFFFFFFu - cidx[b * CAND_CAP + i]);
    }
    keys[i] = kk;
  }
  __syncthreads();
  int K = top_ks[b];
  K = K < 1 ? 1 : (K > 63 ? 63 : K);
  K = K < n ? K : n;
  for (int k = 0; k < K; ++k){
    unsigned long long best = 0ull;
    for (int i = tid; i < CAND_CAP; i += 256){
      unsigned long long xx = keys[i];
      best = xx > best ? xx : best;
    }
#pragma unroll
    for (int off = 32; off; off >>= 1){
      unsigned long long o = __shfl_down(best, off);
      best = o > best ? o : best;
    }
    if ((tid & 63) == 0) red[tid >> 6] = best;
    __syncthreads();
    {
      unsigned long long m01 = red[0] > red[1] ? red[0] : red[1];
      unsigned long long m23 = red[2] > red[3] ? red[2] : red[3];
      best = m01 > m23 ? m01 : m23;
    }
    for (int i = tid; i < CAND_CAP; i += 256)
      if (keys[i] == best) keys[i] = 0ull;
    if (tid == 0){
      tv[b * 64 + k] = ordinv((unsigned)(best >> 32));
      ti[b * 64 + k] = 0xFFFFFFFFu - (unsigned)(best & 0xFFFFFFFFu);
    }
    __syncthreads();
  }
  if (tid == 0) kef[b] = (unsigned)K;
}

// top-p mask on sorted list + gumbel argmax -> token (written as float)
__global__ __launch_bounds__(64) void Sampler_sample(const float* __restrict__ tv,
    const unsigned* __restrict__ ti, const unsigned* __restrict__ kef,
    const float* __restrict__ Mb, const float* __restrict__ Zb,
    const float* __restrict__ top_ps, float* __restrict__ out_tok){
  const int b = blockIdx.x;
  const int k = threadIdx.x;
  const int K = (int)kef[b];
  const float M = Mb[b], Z = Zb[b], tp = top_ps[b];
  float p = 0.f, lv = 0.f; unsigned iv = 0xFFFFFFFFu;
  if (k < K){
    lv = tv[b * 64 + k];
    iv = ti[b * 64 + k];
    p = expf(lv - M) / Z;   // == reference softmax prob
  }
  float incl = p;
#pragma unroll
  for (int off = 1; off < 64; off <<= 1){
    float t = __shfl_up(incl, off);
    if (k >= off) incl += t;
  }
  float excl = incl - p;    // exclusive cumulative prob in sorted order
  float val = -3.4e38f; unsigned idx = 0xFFFFFFFFu;
  if (k < K && excl <= tp){
    val = lv + gumbel_at((uint32_t)b, iv);
    idx = iv;
  }
#pragma unroll
  for (int off = 32; off; off >>= 1){
    float ov = __shfl_down(val, off);
    unsigned oi = __shfl_down(idx, off);
    if (ov > val || (ov == val && oi < idx)){ val = ov; idx = oi; }
  }
  if (k == 0) out_tok[b] = (float)idx;
}

extern "C" void kernel_launch(void* const* d_in, const int* in_sizes, int n_in,
                              void* d_out, int out_size, void* d_ws, size_t ws_size,
                              hipStream_t stream){
  (void)in_sizes; (void)n_in; (void)out_size; (void)ws_size;
  const float* x      = (const float*)d_in[0];
  const float* emb    = (const float*)d_in[1];
  const float* ebias  = (const float*)d_in[2];
  const float* top_ps = (const float*)d_in[3];
  const int*   out_pos= (const int*)d_in[4];
  const int*   top_ks = (const int*)d_in[5];
  // d_in[6] (temp) only selects the sampling branch; value unused.

  float* out    = (float*)d_out;       // [0..63] tokens (as float), then logits [64][V]
  float* logits = out + 64;

  // workspace layout (~1.6 MB)
  float*    hT   = (float*)d_ws;                         // [D_][64]
  float*    Mb   = (float*)((char*)d_ws + (size_t)B_ * D_ * 4);
  float*    Zb   = Mb + 64;
  float*    Tb   = Zb + 64;
  unsigned* cnt  = (unsigned*)(Tb + 64);
  unsigned* kef  = cnt + 64;
  float*    tv   = (float*)(kef + 64);                   // [64][64]
  unsigned* ti   = (unsigned*)(tv + 64 * 64);            // [64][64]
  unsigned* hist = ti + 64 * 64;                         // [64][64]
  float*    cval = (float*)(hist + 64 * 64);             // [64][CAND_CAP]
  unsigned* cidx = (unsigned*)(cval + 64 * CAND_CAP);    // [64][CAND_CAP]

  hipLaunchKernelGGL(Sampler_gather,   dim3((B_ * D_ + 255) / 256), dim3(256), 0, stream, x, out_pos, hT, cnt);
  hipLaunchKernelGGL(Sampler_gemm,     dim3(V_ / 256), dim3(256), 0, stream, hT, emb, ebias, logits);
  hipLaunchKernelGGL(Sampler_rowstats, dim3(64), dim3(1024), 0, stream, logits, Mb, Zb, hist);
  hipLaunchKernelGGL(Sampler_thresh,   dim3(1), dim3(64), 0, stream, hist, Mb, Tb);
  hipLaunchKernelGGL(Sampler_collect,  dim3(64), dim3(1024), 0, stream, logits, Tb, cnt, cval, cidx);
  hipLaunchKernelGGL(Sampler_topk,     dim3(64), dim3(256), 0, stream, cnt, cval, cidx, top_ks, tv, ti, kef);
  hipLaunchKernelGGL(Sampler_sample,   dim3(64), dim3(64), 0, stream, tv, ti, kef, Mb, Zb, top_ps, out);
}

// Round 2
// 493.913 us; speedup vs baseline: 1.3260x; 1.3260x over previous
//
#include <hip/hip_runtime.h>
#include <cstdint>
#include <cstddef>

#define B_ 64
#define S_ 8
#define D_ 2048
#define V_ 128000
#define CAND_CAP 2048

typedef __bf16 v8bf __attribute__((ext_vector_type(8)));
typedef float  v4f  __attribute__((ext_vector_type(4)));

// ---------------- threefry2x32 (JAX-compatible) ----------------
__device__ __forceinline__ uint32_t rotl32(uint32_t x, int r){ return (x << r) | (x >> (32 - r)); }
__device__ __forceinline__ void tfround(uint32_t& x0, uint32_t& x1, int r){
  x0 += x1; x1 = rotl32(x1, r); x1 ^= x0;
}
__device__ __forceinline__ void threefry2x32(uint32_t k0, uint32_t k1, uint32_t c0, uint32_t c1,
                                             uint32_t& o0, uint32_t& o1){
  uint32_t ks2 = k0 ^ k1 ^ 0x1BD11BDAu;
  uint32_t x0 = c0 + k0, x1 = c1 + k1;
  tfround(x0,x1,13); tfround(x0,x1,15); tfround(x0,x1,26); tfround(x0,x1,6);
  x0 += k1; x1 += ks2 + 1u;
  tfround(x0,x1,17); tfround(x0,x1,29); tfround(x0,x1,16); tfround(x0,x1,24);
  x0 += ks2; x1 += k0 + 2u;
  tfround(x0,x1,13); tfround(x0,x1,15); tfround(x0,x1,26); tfround(x0,x1,6);
  x0 += k0; x1 += k1 + 3u;
  tfround(x0,x1,17); tfround(x0,x1,29); tfround(x0,x1,16); tfround(x0,x1,24);
  x0 += k1; x1 += ks2 + 4u;
  tfround(x0,x1,13); tfround(x0,x1,15); tfround(x0,x1,26); tfround(x0,x1,6);
  x0 += ks2; x1 += k0 + 5u;
  o0 = x0; o1 = x1;
}

#define JAX_PARTITIONABLE 1

__device__ __forceinline__ float gumbel_at(uint32_t b, uint32_t v){
  uint32_t j = b * (uint32_t)V_ + v;
  uint32_t bits;
#if JAX_PARTITIONABLE
  uint32_t o0, o1; threefry2x32(0u, 42u, 0u, j, o0, o1);
  bits = o0 ^ o1;
#else
  const uint32_t HALF = 4096000u;  // B*V/2
  uint32_t o0, o1;
  if (j < HALF){ threefry2x32(0u, 42u, j, j + HALF, o0, o1); bits = o0; }
  else        { threefry2x32(0u, 42u, j - HALF, j, o0, o1); bits = o1; }
#endif
  uint32_t fb = (bits >> 9) | 0x3F800000u;
  float f = __uint_as_float(fb) - 1.0f;
  const float TINY = 1.17549435e-38f;
  float u = fmaxf(TINY, f + TINY);
  return -logf(-logf(u));
}

__device__ __forceinline__ unsigned ordkey(float f){
  unsigned u = __float_as_uint(f);
  return (u & 0x80000000u) ? ~u : (u | 0x80000000u);
}
__device__ __forceinline__ float ordinv(unsigned o){
  unsigned u = (o & 0x80000000u) ? (o & 0x7FFFFFFFu) : ~o;
  return __uint_as_float(u);
}

__device__ __forceinline__ v8bf ld_bf8(const unsigned short* p){
  uint4 u = *reinterpret_cast<const uint4*>(p);
  return __builtin_bit_cast(v8bf, u);
}

// ---------------- kernels ----------------

// gather h at out_pos, split fp32 -> bf16 hi/lo ([b][k] row-major), zero counters
__global__ __launch_bounds__(256) void Sampler_gather(const float* __restrict__ x,
    const int* __restrict__ out_pos, unsigned short* __restrict__ hhi,
    unsigned short* __restrict__ hlo, unsigned* __restrict__ cnt){
  const int pos = out_pos[0];
  int i = blockIdx.x * 256 + threadIdx.x;
  if (i < B_ * D_){
    int bq = i >> 11;          // b
    int kq = i & 2047;         // k
    float v = x[((size_t)bq * S_ + pos) * D_ + kq];
    __bf16 hb = (__bf16)v;
    float hf = (float)hb;
    __bf16 lb = (__bf16)(v - hf);
    hhi[i] = __builtin_bit_cast(unsigned short, hb);
    hlo[i] = __builtin_bit_cast(unsigned short, lb);
  }
  if (i < 64) cnt[i] = 0;
}

// Split-bf16 MFMA GEMM: logits[b][v] = sum_k h[b][k]*emb[v][k] + bias[v]
// Per wave: 64(M) x 64(N) tile, direct-from-global fragments, no LDS.
// A frag (16x16x32): m=lane&15, k=8*(lane>>4)+i ; B frag: n=lane&15, k=8*(lane>>4)+i
// C/D: col(n)=lane&15, row(m)=4*(lane>>4)+reg   [verified layout]
__global__ __launch_bounds__(256, 2) void Sampler_gemm(
    const unsigned short* __restrict__ hhi,  // [64][2048] bf16 hi
    const unsigned short* __restrict__ hlo,  // [64][2048] bf16 lo
    const float* __restrict__ emb,           // [V_][D_]
    const float* __restrict__ bias,          // [V_]
    float* __restrict__ out)                 // [64][V_]
{
  const int tid  = threadIdx.x;
  const int wid  = tid >> 6;
  const int lane = tid & 63;
  const int r16  = lane & 15;
  const int kg   = lane >> 4;          // 0..3
  const int vbase = (blockIdx.x << 8) + (wid << 6);

  // per-lane base offsets (elements)
  const int arow = r16 * D_ + 8 * kg;                 // into hhi/hlo
  const float* bptr[4];
#pragma unroll
  for (int ni = 0; ni < 4; ++ni)
    bptr[ni] = emb + (size_t)(vbase + 16 * ni + r16) * D_ + 8 * kg;

  v4f acc[4][4];
#pragma unroll
  for (int mi = 0; mi < 4; ++mi)
#pragma unroll
    for (int ni = 0; ni < 4; ++ni) acc[mi][ni] = (v4f){0.f, 0.f, 0.f, 0.f};

  float4 sA[4][2], sB[4][2];

  auto LOADB = [&](int ks, float4 (&bs)[4][2]){
#pragma unroll
    for (int ni = 0; ni < 4; ++ni){
      const float* p = bptr[ni] + 32 * ks;
      bs[ni][0] = *reinterpret_cast<const float4*>(p);
      bs[ni][1] = *reinterpret_cast<const float4*>(p + 4);
    }
  };

  auto STEP = [&](const float4 (&bs)[4][2], int ks){
    // A fragments (L2-resident)
    v8bf ah[4], al[4];
    const unsigned short* hh = hhi + arow + 32 * ks;
    const unsigned short* hl = hlo + arow + 32 * ks;
#pragma unroll
    for (int mi = 0; mi < 4; ++mi){
      ah[mi] = ld_bf8(hh + mi * (16 * D_));
      al[mi] = ld_bf8(hl + mi * (16 * D_));
    }
#pragma unroll
    for (int ni = 0; ni < 4; ++ni){
      float xf[8] = { bs[ni][0].x, bs[ni][0].y, bs[ni][0].z, bs[ni][0].w,
                      bs[ni][1].x, bs[ni][1].y, bs[ni][1].z, bs[ni][1].w };
      v8bf bh, bl;
#pragma unroll
      for (int j = 0; j < 8; ++j){
        float v = xf[j];
        __bf16 hb = (__bf16)v;
        float hf = (float)hb;
        bh[j] = hb;
        bl[j] = (__bf16)(v - hf);
      }
#pragma unroll
      for (int mi = 0; mi < 4; ++mi){
        acc[mi][ni] = __builtin_amdgcn_mfma_f32_16x16x32_bf16(ah[mi], bh, acc[mi][ni], 0, 0, 0);
        acc[mi][ni] = __builtin_amdgcn_mfma_f32_16x16x32_bf16(al[mi], bh, acc[mi][ni], 0, 0, 0);
        acc[mi][ni] = __builtin_amdgcn_mfma_f32_16x16x32_bf16(ah[mi], bl, acc[mi][ni], 0, 0, 0);
      }
    }
  };

  LOADB(0, sA);
#pragma unroll 1
  for (int ks = 0; ks < 64; ks += 2){
    LOADB(ks + 1, sB);
    STEP(sA, ks);
    if (ks + 2 < 64) LOADB(ks + 2, sA);
    STEP(sB, ks + 1);
  }

  // epilogue: + bias
#pragma unroll
  for (int ni = 0; ni < 4; ++ni){
    const int v = vbase + 16 * ni + r16;
    const float bv = bias[v];
#pragma unroll
    for (int mi = 0; mi < 4; ++mi){
#pragma unroll
      for (int r = 0; r < 4; ++r){
        const int b = 16 * mi + 4 * kg + r;
        out[(size_t)b * V_ + v] = acc[mi][ni][r] + bv;
      }
    }
  }
}

// per-row max, softmax denom Z, and 64-bin histogram of (M - l) with bin width 0.125
__global__ __launch_bounds__(1024) void Sampler_rowstats(const float* __restrict__ logits,
    float* __restrict__ Mb, float* __restrict__ Zb, unsigned* __restrict__ hist){
  __shared__ float red[16];
  __shared__ float sM;
  __shared__ unsigned wh[16][64];
  const int b = blockIdx.x;
  const int tid = threadIdx.x;
  const int lane = tid & 63, wid = tid >> 6;
  const float* row = logits + (size_t)b * V_;

  float m = -3.4e38f;
  for (int i = tid; i < V_; i += 1024) m = fmaxf(m, row[i]);
#pragma unroll
  for (int off = 32; off; off >>= 1) m = fmaxf(m, __shfl_down(m, off));
  if (lane == 0) red[wid] = m;
  __syncthreads();
  if (tid == 0){
    float mm = red[0];
    for (int i = 1; i < 16; ++i) mm = fmaxf(mm, red[i]);
    sM = mm;
  }
  for (int i = tid; i < 16 * 64; i += 1024) ((unsigned*)wh)[i] = 0;
  __syncthreads();

  const float M = sM;
  float z = 0.f;
  for (int i = tid; i < V_; i += 1024){
    float l = row[i];
    z += expf(l - M);
    int bin = (int)((M - l) * 8.0f);
    bin = bin > 63 ? 63 : bin;
    atomicAdd(&wh[wid][bin], 1u);
  }
#pragma unroll
  for (int off = 32; off; off >>= 1) z += __shfl_down(z, off);
  __syncthreads();
  if (lane == 0) red[wid] = z;
  __syncthreads();
  if (tid == 0){
    float zz = 0.f;
    for (int i = 0; i < 16; ++i) zz += red[i];
    Zb[b] = zz; Mb[b] = M;
  }
  if (tid < 64){
    unsigned s = 0;
#pragma unroll
    for (int w = 0; w < 16; ++w) s += wh[w][tid];
    hist[b * 64 + tid] = s;
  }
}

// pick per-row collection threshold: smallest bin with cumulative count >= 128 (>= K_max=63)
__global__ __launch_bounds__(64) void Sampler_thresh(const unsigned* __restrict__ hist,
    const float* __restrict__ Mb, float* __restrict__ Tb){
  const int b = threadIdx.x;
  unsigned cum = 0; int chosen = 63;
  for (int i = 0; i < 64; ++i){
    cum += hist[b * 64 + i];
    if (cum >= 128u){ chosen = i; break; }
  }
  Tb[b] = Mb[b] - 0.125f * (float)(chosen + 1);
}

// collect candidates l > T
__global__ __launch_bounds__(1024) void Sampler_collect(const float* __restrict__ logits,
    const float* __restrict__ Tb, unsigned* __restrict__ cnt,
    float* __restrict__ cval, unsigned* __restrict__ cidx){
  const int b = blockIdx.x;
  const float T = Tb[b];
  const float* row = logits + (size_t)b * V_;
  for (int i = threadIdx.x; i < V_; i += 1024){
    float l = row[i];
    if (l > T){
      unsigned pz = atomicAdd(&cnt[b], 1u);
      if (pz < CAND_CAP){ cval[b * CAND_CAP + pz] = l; cidx[b * CAND_CAP + pz] = (unsigned)i; }
    }
  }
}

// extract top-K (stable: value desc, index asc) by iterative argmax over candidates
__global__ __launch_bounds__(256) void Sampler_topk(const unsigned* __restrict__ cnt,
    const float* __restrict__ cval, const unsigned* __restrict__ cidx,
    const int* __restrict__ top_ks, float* __restrict__ tv, unsigned* __restrict__ ti,
    unsigned* __restrict__ kef){
  __shared__ unsigned long long keys[CAND_CAP];
  __shared__ unsigned long long red[4];
  const int b = blockIdx.x;
  const int tid = threadIdx.x;
  int n = (int)min(cnt[b], (unsigned)CAND_CAP);
  for (int i = tid; i < CAND_CAP; i += 256){
    unsigned long long kk = 0ull;
    if (i < n){
      unsigned o = ordkey(cval[b * CAND_CAP + i]);
      kk = ((unsigned long long)o << 32) | (unsigned long long)(0xFFFFFFFFu - cidx[b * CAND_CAP + i]);
    }
    keys[i] = kk;
  }
  __syncthreads();
  int K = top_ks[b];
  K = K < 1 ? 1 : (K > 63 ? 63 : K);
  K = K < n ? K : n;
  for (int k = 0; k < K; ++k){
    unsigned long long best = 0ull;
    for (int i = tid; i < CAND_CAP; i += 256){
      unsigned long long xx = keys[i];
      best = xx > best ? xx : best;
    }
#pragma unroll
    for (int off = 32; off; off >>= 1){
      unsigned long long o = __shfl_down(best, off);
      best = o > best ? o : best;
    }
    if ((tid & 63) == 0) red[tid >> 6] = best;
    __syncthreads();
    {
      unsigned long long m01 = red[0] > red[1] ? red[0] : red[1];
      unsigned long long m23 = red[2] > red[3] ? red[2] : red[3];
      best = m01 > m23 ? m01 : m23;
    }
    for (int i = tid; i < CAND_CAP; i += 256)
      if (keys[i] == best) keys[i] = 0ull;
    if (tid == 0){
      tv[b * 64 + k] = ordinv((unsigned)(best >> 32));
      ti[b * 64 + k] = 0xFFFFFFFFu - (unsigned)(best & 0xFFFFFFFFu);
    }
    __syncthreads();
  }
  if (tid == 0) kef[b] = (unsigned)K;
}

// top-p mask on sorted list + gumbel argmax -> token (written as float)
__global__ __launch_bounds__(64) void Sampler_sample(const float* __restrict__ tv,
    const unsigned* __restrict__ ti, const unsigned* __restrict__ kef,
    const float* __restrict__ Mb, const float* __restrict__ Zb,
    const float* __restrict__ top_ps, float* __restrict__ out_tok){
  const int b = blockIdx.x;
  const int k = threadIdx.x;
  const int K = (int)kef[b];
  const float M = Mb[b], Z = Zb[b], tp = top_ps[b];
  float p = 0.f, lv = 0.f; unsigned iv = 0xFFFFFFFFu;
  if (k < K){
    lv = tv[b * 64 + k];
    iv = ti[b * 64 + k];
    p = expf(lv - M) / Z;
  }
  float incl = p;
#pragma unroll
  for (int off = 1; off < 64; off <<= 1){
    float t = __shfl_up(incl, off);
    if (k >= off) incl += t;
  }
  float excl = incl - p;
  float val = -3.4e38f; unsigned idx = 0xFFFFFFFFu;
  if (k < K && excl <= tp){
    val = lv + gumbel_at((uint32_t)b, iv);
    idx = iv;
  }
#pragma unroll
  for (int off = 32; off; off >>= 1){
    float ov = __shfl_down(val, off);
    unsigned oi = __shfl_down(idx, off);
    if (ov > val || (ov == val && oi < idx)){ val = ov; idx = oi; }
  }
  if (k == 0) out_tok[b] = (float)idx;
}

extern "C" void kernel_launch(void* const* d_in, const int* in_sizes, int n_in,
                              void* d_out, int out_size, void* d_ws, size_t ws_size,
                              hipStream_t stream){
  (void)in_sizes; (void)n_in; (void)out_size; (void)ws_size;
  const float* x      = (const float*)d_in[0];
  const float* emb    = (const float*)d_in[1];
  const float* ebias  = (const float*)d_in[2];
  const float* top_ps = (const float*)d_in[3];
  const int*   out_pos= (const int*)d_in[4];
  const int*   top_ks = (const int*)d_in[5];

  float* out    = (float*)d_out;       // [0..63] tokens (as float), then logits [64][V]
  float* logits = out + 64;

  // workspace layout (~1.6 MB)
  unsigned short* hhi = (unsigned short*)d_ws;                    // [64][2048] bf16
  unsigned short* hlo = hhi + (size_t)B_ * D_;                    // [64][2048] bf16
  float*    Mb   = (float*)((char*)d_ws + (size_t)B_ * D_ * 4);   // after 512KB
  float*    Zb   = Mb + 64;
  float*    Tb   = Zb + 64;
  unsigned* cnt  = (unsigned*)(Tb + 64);
  unsigned* kef  = cnt + 64;
  float*    tv   = (float*)(kef + 64);                   // [64][64]
  unsigned* ti   = (unsigned*)(tv + 64 * 64);            // [64][64]
  unsigned* hist = ti + 64 * 64;                         // [64][64]
  float*    cval = (float*)(hist + 64 * 64);             // [64][CAND_CAP]
  unsigned* cidx = (unsigned*)(cval + 64 * CAND_CAP);    // [64][CAND_CAP]

  hipLaunchKernelGGL(Sampler_gather,   dim3((B_ * D_ + 255) / 256), dim3(256), 0, stream, x, out_pos, hhi, hlo, cnt);
  hipLaunchKernelGGL(Sampler_gemm,     dim3(V_ / 256), dim3(256), 0, stream, hhi, hlo, emb, ebias, logits);
  hipLaunchKernelGGL(Sampler_rowstats, dim3(64), dim3(1024), 0, stream, logits, Mb, Zb, hist);
  hipLaunchKernelGGL(Sampler_thresh,   dim3(1), dim3(64), 0, stream, hist, Mb, Tb);
  hipLaunchKernelGGL(Sampler_collect,  dim3(64), dim3(1024), 0, stream, logits, Tb, cnt, cval, cidx);
  hipLaunchKernelGGL(Sampler_topk,     dim3(64), dim3(256), 0, stream, cnt, cval, cidx, top_ks, tv, ti, kef);
  hipLaunchKernelGGL(Sampler_sample,   dim3(64), dim3(64), 0, stream, tv, ti, kef, Mb, Zb, top_ps, out);
}

// Round 4
// 382.960 us; speedup vs baseline: 1.7102x; 1.2897x over previous
//
#include <hip/hip_runtime.h>
#include <cstdint>
#include <cstddef>

#define B_ 64
#define S_ 8
#define D_ 2048
#define V_ 128000
#define CAND_CAP 4096

typedef __bf16 v8bf __attribute__((ext_vector_type(8)));
typedef float  v4f  __attribute__((ext_vector_type(4)));

#define GLOBAL_AS __attribute__((address_space(1)))
#define LDS_AS    __attribute__((address_space(3)))

__device__ __forceinline__ void gload_lds16(const float* g, float* l){
  __builtin_amdgcn_global_load_lds((const GLOBAL_AS uint32_t*)g, (LDS_AS uint32_t*)l, 16, 0, 0);
}

// ---------------- threefry2x32 (JAX-compatible) ----------------
__device__ __forceinline__ uint32_t rotl32(uint32_t x, int r){ return (x << r) | (x >> (32 - r)); }
__device__ __forceinline__ void tfround(uint32_t& x0, uint32_t& x1, int r){
  x0 += x1; x1 = rotl32(x1, r); x1 ^= x0;
}
__device__ __forceinline__ void threefry2x32(uint32_t k0, uint32_t k1, uint32_t c0, uint32_t c1,
                                             uint32_t& o0, uint32_t& o1){
  uint32_t ks2 = k0 ^ k1 ^ 0x1BD11BDAu;
  uint32_t x0 = c0 + k0, x1 = c1 + k1;
  tfround(x0,x1,13); tfround(x0,x1,15); tfround(x0,x1,26); tfround(x0,x1,6);
  x0 += k1; x1 += ks2 + 1u;
  tfround(x0,x1,17); tfround(x0,x1,29); tfround(x0,x1,16); tfround(x0,x1,24);
  x0 += ks2; x1 += k0 + 2u;
  tfround(x0,x1,13); tfround(x0,x1,15); tfround(x0,x1,26); tfround(x0,x1,6);
  x0 += k0; x1 += k1 + 3u;
  tfround(x0,x1,17); tfround(x0,x1,29); tfround(x0,x1,16); tfround(x0,x1,24);
  x0 += k1; x1 += ks2 + 4u;
  tfround(x0,x1,13); tfround(x0,x1,15); tfround(x0,x1,26); tfround(x0,x1,6);
  x0 += ks2; x1 += k0 + 5u;
  o0 = x0; o1 = x1;
}

#define JAX_PARTITIONABLE 1

__device__ __forceinline__ float gumbel_at(uint32_t b, uint32_t v){
  uint32_t j = b * (uint32_t)V_ + v;
  uint32_t bits;
#if JAX_PARTITIONABLE
  uint32_t o0, o1; threefry2x32(0u, 42u, 0u, j, o0, o1);
  bits = o0 ^ o1;
#else
  const uint32_t HALF = 4096000u;  // B*V/2
  uint32_t o0, o1;
  if (j < HALF){ threefry2x32(0u, 42u, j, j + HALF, o0, o1); bits = o0; }
  else        { threefry2x32(0u, 42u, j - HALF, j, o0, o1); bits = o1; }
#endif
  uint32_t fb = (bits >> 9) | 0x3F800000u;
  float f = __uint_as_float(fb) - 1.0f;
  const float TINY = 1.17549435e-38f;
  float u = fmaxf(TINY, f + TINY);
  return -logf(-logf(u));
}

__device__ __forceinline__ unsigned ordkey(float f){
  unsigned u = __float_as_uint(f);
  return (u & 0x80000000u) ? ~u : (u | 0x80000000u);
}
__device__ __forceinline__ float ordinv(unsigned o){
  unsigned u = (o & 0x80000000u) ? (o & 0x7FFFFFFFu) : ~o;
  return __uint_as_float(u);
}

__device__ __forceinline__ v8bf ld_bf8(const unsigned short* p){
  uint4 u = *reinterpret_cast<const uint4*>(p);
  return __builtin_bit_cast(v8bf, u);
}

// ---------------- kernels ----------------

// gather h at out_pos, split fp32 -> bf16 hi/lo ([b][k] row-major), zero counters + hist
__global__ __launch_bounds__(256) void Sampler_gather(const float* __restrict__ x,
    const int* __restrict__ out_pos, unsigned short* __restrict__ hhi,
    unsigned short* __restrict__ hlo, unsigned* __restrict__ cnt,
    unsigned* __restrict__ Mo, unsigned* __restrict__ hist){
  const int pos = out_pos[0];
  int i = blockIdx.x * 256 + threadIdx.x;
  if (i < B_ * D_){
    int bq = i >> 11;          // b
    int kq = i & 2047;         // k
    float v = x[((size_t)bq * S_ + pos) * D_ + kq];
    __bf16 hb = (__bf16)v;
    float hf = (float)hb;
    __bf16 lb = (__bf16)(v - hf);
    hhi[i] = __builtin_bit_cast(unsigned short, hb);
    hlo[i] = __builtin_bit_cast(unsigned short, lb);
  }
  if (i < 64){ cnt[i] = 0; Mo[i] = 0; }
  if (i < 64 * 32) hist[i] = 0;
}

// Split-bf16 MFMA GEMM with LDS-staged B (2-phase, global_load_lds, XOR swizzle).
// logits[b][v] = sum_k h[b][k]*emb[v][k] + bias[v]
// Block: 256 threads (4 waves), N-tile 256 (64 per wave), BK=32.
// LDS tile: [256 rows][8 granules of 16B]; phys granule c holds logical c ^ (row&7).
__global__ __launch_bounds__(256, 2) void Sampler_gemm(
    const unsigned short* __restrict__ hhi,  // [64][2048] bf16 hi
    const unsigned short* __restrict__ hlo,  // [64][2048] bf16 lo
    const float* __restrict__ emb,           // [V_][D_]
    const float* __restrict__ bias,          // [V_]
    float* __restrict__ out)                 // [64][V_]
{
  __shared__ float Bs[2][256 * 32];          // 2 x 32 KB
  const int tid  = threadIdx.x;
  const int wid  = tid >> 6;
  const int lane = tid & 63;
  const int r16  = lane & 15;
  const int kg   = lane >> 4;                // 0..3
  const int vbase = (blockIdx.x << 8) + (wid << 6);

  // staging constants: thread t stages dst bytes t*16 + p*4096 (p=0..7)
  const int srow = tid >> 3;                 // row within 32-row p-group
  const int hsrc = (tid & 7) ^ (srow & 7);   // inverse-swizzled source granule
  const float* sbase = emb + (size_t)((blockIdx.x << 8) + srow) * D_ + hsrc * 4;

  // read constants: phys granules for this lane's k-slice (row&7 == r16&7)
  const int h0 = ((2 * kg)     ^ (r16 & 7)) * 4;  // in floats
  const int h1 = ((2 * kg + 1) ^ (r16 & 7)) * 4;

  v4f acc[4][4];
#pragma unroll
  for (int mi = 0; mi < 4; ++mi)
#pragma unroll
    for (int ni = 0; ni < 4; ++ni) acc[mi][ni] = (v4f){0.f, 0.f, 0.f, 0.f};

  const unsigned short* hhb = hhi + r16 * D_ + 8 * kg;
  const unsigned short* hlb = hlo + r16 * D_ + 8 * kg;

  // prologue: stage chunk 0
#pragma unroll
  for (int p = 0; p < 8; ++p)
    gload_lds16(sbase + (size_t)p * 32 * D_, &Bs[0][tid * 4 + p * 1024]);
  __syncthreads();

#pragma unroll 1
  for (int c = 0; c < 64; ++c){
    const int k0 = c * 32;
    const int cur = c & 1;

    // A fragments (L2-resident)
    v8bf ah[4], al[4];
#pragma unroll
    for (int mi = 0; mi < 4; ++mi){
      ah[mi] = ld_bf8(hhb + k0 + mi * (16 * D_));
      al[mi] = ld_bf8(hlb + k0 + mi * (16 * D_));
    }

    // stage next chunk into the other buffer
    if (c + 1 < 64){
#pragma unroll
      for (int p = 0; p < 8; ++p)
        gload_lds16(sbase + (size_t)p * 32 * D_ + (k0 + 32),
                    &Bs[cur ^ 1][tid * 4 + p * 1024]);
    }

    // compute from current buffer
#pragma unroll
    for (int ni = 0; ni < 4; ++ni){
      const int r = (wid << 6) + (ni << 4) + r16;
      const float* bp = &Bs[cur][r * 32];
      float4 b0 = *(const float4*)(bp + h0);   // k = k0+8kg .. +3
      float4 b1 = *(const float4*)(bp + h1);   // k = k0+8kg+4 .. +7
      float xf[8] = { b0.x, b0.y, b0.z, b0.w, b1.x, b1.y, b1.z, b1.w };
      v8bf bh, bl;
#pragma unroll
      for (int j = 0; j < 8; ++j){
        float v = xf[j];
        __bf16 hb = (__bf16)v;
        float hf = (float)hb;
        bh[j] = hb;
        bl[j] = (__bf16)(v - hf);
      }
#pragma unroll
      for (int mi = 0; mi < 4; ++mi){
        acc[mi][ni] = __builtin_amdgcn_mfma_f32_16x16x32_bf16(ah[mi], bh, acc[mi][ni], 0, 0, 0);
        acc[mi][ni] = __builtin_amdgcn_mfma_f32_16x16x32_bf16(al[mi], bh, acc[mi][ni], 0, 0, 0);
        acc[mi][ni] = __builtin_amdgcn_mfma_f32_16x16x32_bf16(ah[mi], bl, acc[mi][ni], 0, 0, 0);
      }
    }
    __syncthreads();   // drains vmcnt(0): next buffer complete; LDS WAR safe
  }

  // epilogue: + bias
#pragma unroll
  for (int ni = 0; ni < 4; ++ni){
    const int v = vbase + 16 * ni + r16;
    const float bv = bias[v];
#pragma unroll
    for (int mi = 0; mi < 4; ++mi){
#pragma unroll
      for (int r = 0; r < 4; ++r){
        const int b = 16 * mi + 4 * kg + r;
        out[(size_t)b * V_ + v] = acc[mi][ni][r] + bv;
      }
    }
  }
}

// per-row max via 4 column-slices per row, atomicMax on ordkey
__global__ __launch_bounds__(256) void Sampler_rowmax(const float* __restrict__ logits,
    unsigned* __restrict__ Mo){
  __shared__ float red[4];
  const int b = blockIdx.x >> 2, sl = blockIdx.x & 3;
  const int tid = threadIdx.x;
  const float4* row = (const float4*)(logits + (size_t)b * V_ + sl * 32000);
  float m = -3.4e38f;
  for (int i = tid; i < 8000; i += 256){
    float4 v = row[i];
    m = fmaxf(m, fmaxf(fmaxf(v.x, v.y), fmaxf(v.z, v.w)));
  }
#pragma unroll
  for (int off = 32; off; off >>= 1) m = fmaxf(m, __shfl_down(m, off));
  if ((tid & 63) == 0) red[tid >> 6] = m;
  __syncthreads();
  if (tid == 0){
    m = fmaxf(fmaxf(red[0], red[1]), fmaxf(red[2], red[3]));
    atomicMax(&Mo[b], ordkey(m));
  }
}

// fused: deterministic softmax-denom partials + 32-bin histogram of (M-l), width 0.125,
// atomics only for the ~2k/row elements with M-l < 4 (the only bins the threshold scan needs)
__global__ __launch_bounds__(256) void Sampler_zcount(const float* __restrict__ logits,
    const unsigned* __restrict__ Mo, float* __restrict__ Mb, float* __restrict__ Zp,
    unsigned* __restrict__ hist){
  __shared__ float red[4];
  __shared__ unsigned wh[32];
  const int b = blockIdx.x >> 2, sl = blockIdx.x & 3;
  const int tid = threadIdx.x;
  const float M = ordinv(Mo[b]);
  const float4* row = (const float4*)(logits + (size_t)b * V_ + sl * 32000);
  if (tid < 32) wh[tid] = 0;
  __syncthreads();
  float z = 0.f;
  for (int i = tid; i < 8000; i += 256){
    float4 v = row[i];
    float d0 = M - v.x, d1 = M - v.y, d2 = M - v.z, d3 = M - v.w;
    z += expf(-d0); z += expf(-d1); z += expf(-d2); z += expf(-d3);
    if (d0 < 4.f) atomicAdd(&wh[(int)(d0 * 8.f)], 1u);
    if (d1 < 4.f) atomicAdd(&wh[(int)(d1 * 8.f)], 1u);
    if (d2 < 4.f) atomicAdd(&wh[(int)(d2 * 8.f)], 1u);
    if (d3 < 4.f) atomicAdd(&wh[(int)(d3 * 8.f)], 1u);
  }
#pragma unroll
  for (int off = 32; off; off >>= 1) z += __shfl_down(z, off);
  if ((tid & 63) == 0) red[tid >> 6] = z;
  __syncthreads();
  if (tid == 0){
    Zp[b * 4 + sl] = ((red[0] + red[1]) + red[2]) + red[3];
    if (sl == 0) Mb[b] = M;
  }
  if (tid < 32 && wh[tid]) atomicAdd(&hist[b * 32 + tid], wh[tid]);
}

// pick per-row collection threshold: smallest bin with cumulative count >= 96 (>= K_max=63)
__global__ __launch_bounds__(64) void Sampler_thresh(const unsigned* __restrict__ hist,
    const float* __restrict__ Mb, float* __restrict__ Tb){
  const int b = threadIdx.x;
  unsigned cum = 0; int chosen = 31;
  for (int i = 0; i < 32; ++i){
    cum += hist[b * 32 + i];
    if (cum >= 96u){ chosen = i; break; }
  }
  Tb[b] = Mb[b] - 0.125f * (float)(chosen + 1);
}

// collect candidates l > T
__global__ __launch_bounds__(256) void Sampler_collect(const float* __restrict__ logits,
    const float* __restrict__ Tb, unsigned* __restrict__ cnt,
    float* __restrict__ cval, unsigned* __restrict__ cidx){
  const int b = blockIdx.x >> 2, sl = blockIdx.x & 3;
  const int base = sl * 32000;
  const float T = Tb[b];
  const float4* row = (const float4*)(logits + (size_t)b * V_ + base);
  for (int i = threadIdx.x; i < 8000; i += 256){
    float4 v = row[i];
    float vv[4] = {v.x, v.y, v.z, v.w};
#pragma unroll
    for (int j = 0; j < 4; ++j){
      if (vv[j] > T){
        unsigned pz = atomicAdd(&cnt[b], 1u);
        if (pz < CAND_CAP){
          cval[b * CAND_CAP + pz] = vv[j];
          cidx[b * CAND_CAP + pz] = (unsigned)(base + i * 4 + j);
        }
      }
    }
  }
}

// extract top-K (stable: value desc, index asc) by iterative argmax over candidates
__global__ __launch_bounds__(256) void Sampler_topk(const unsigned* __restrict__ cnt,
    const float* __restrict__ cval, const unsigned* __restrict__ cidx,
    const int* __restrict__ top_ks, float* __restrict__ tv, unsigned* __restrict__ ti,
    unsigned* __restrict__ kef){
  __shared__ unsigned long long keys[CAND_CAP];
  __shared__ unsigned long long red[4];
  const int b = blockIdx.x;
  const int tid = threadIdx.x;
  int n = (int)min(cnt[b], (unsigned)CAND_CAP);
  const int nr = (n + 255) & ~255;           // scan bound, multiple of 256
  for (int i = tid; i < nr; i += 256){
    unsigned long long kk = 0ull;
    if (i < n){
      unsigned o = ordkey(cval[b * CAND_CAP + i]);
      kk = ((unsigned long long)o << 32) | (unsigned long long)(0xFFFFFFFFu - cidx[b * CAND_CAP + i]);
    }
    keys[i] = kk;
  }
  __syncthreads();
  int K = top_ks[b];
  K = K < 1 ? 1 : (K > 63 ? 63 : K);
  K = K < n ? K : n;
  for (int k = 0; k < K; ++k){
    unsigned long long best = 0ull;
    for (int i = tid; i < nr; i += 256){
      unsigned long long xx = keys[i];
      best = xx > best ? xx : best;
    }
#pragma unroll
    for (int off = 32; off; off >>= 1){
      unsigned long long o = __shfl_down(best, off);
      best = o > best ? o : best;
    }
    if ((tid & 63) == 0) red[tid >> 6] = best;
    __syncthreads();
    {
      unsigned long long m01 = red[0] > red[1] ? red[0] : red[1];
      unsigned long long m23 = red[2] > red[3] ? red[2] : red[3];
      best = m01 > m23 ? m01 : m23;
    }
    for (int i = tid; i < nr; i += 256)
      if (keys[i] == best) keys[i] = 0ull;
    if (tid == 0){
      tv[b * 64 + k] = ordinv((unsigned)(best >> 32));
      ti[b * 64 + k] = 0xFFFFFFFFu - (unsigned)(best & 0xFFFFFFFFu);
    }
    __syncthreads();
  }
  if (tid == 0) kef[b] = (unsigned)K;
}

// top-p mask on sorted list + gumbel argmax -> token (written as float)
__global__ __launch_bounds__(64) void Sampler_sample(const float* __restrict__ tv,
    const unsigned* __restrict__ ti, const unsigned* __restrict__ kef,
    const float* __restrict__ Mb, const float* __restrict__ Zp,
    const float* __restrict__ top_ps, float* __restrict__ out_tok){
  const int b = blockIdx.x;
  const int k = threadIdx.x;
  const int K = (int)kef[b];
  const float M = Mb[b], tp = top_ps[b];
  const float Z = ((Zp[b * 4 + 0] + Zp[b * 4 + 1]) + Zp[b * 4 + 2]) + Zp[b * 4 + 3];
  float p = 0.f, lv = 0.f; unsigned iv = 0xFFFFFFFFu;
  if (k < K){
    lv = tv[b * 64 + k];
    iv = ti[b * 64 + k];
    p = expf(lv - M) / Z;
  }
  float incl = p;
#pragma unroll
  for (int off = 1; off < 64; off <<= 1){
    float t = __shfl_up(incl, off);
    if (k >= off) incl += t;
  }
  float excl = incl - p;
  float val = -3.4e38f; unsigned idx = 0xFFFFFFFFu;
  if (k < K && excl <= tp){
    val = lv + gumbel_at((uint32_t)b, iv);
    idx = iv;
  }
#pragma unroll
  for (int off = 32; off; off >>= 1){
    float ov = __shfl_down(val, off);
    unsigned oi = __shfl_down(idx, off);
    if (ov > val || (ov == val && oi < idx)){ val = ov; idx = oi; }
  }
  if (k == 0) out_tok[b] = (float)idx;
}

extern "C" void kernel_launch(void* const* d_in, const int* in_sizes, int n_in,
                              void* d_out, int out_size, void* d_ws, size_t ws_size,
                              hipStream_t stream){
  (void)in_sizes; (void)n_in; (void)out_size; (void)ws_size;
  const float* x      = (const float*)d_in[0];
  const float* emb    = (const float*)d_in[1];
  const float* ebias  = (const float*)d_in[2];
  const float* top_ps = (const float*)d_in[3];
  const int*   out_pos= (const int*)d_in[4];
  const int*   top_ks = (const int*)d_in[5];

  float* out    = (float*)d_out;       // [0..63] tokens (as float), then logits [64][V]
  float* logits = out + 64;

  // workspace layout (~2.6 MB)
  unsigned short* hhi = (unsigned short*)d_ws;                    // [64][2048] bf16
  unsigned short* hlo = hhi + (size_t)B_ * D_;                    // [64][2048] bf16
  char* wp = (char*)d_ws + (size_t)B_ * D_ * 4;                   // after 512KB
  unsigned* Mo   = (unsigned*)wp;          wp += 64 * 4;
  float*    Mb   = (float*)wp;             wp += 64 * 4;
  float*    Tb   = (float*)wp;             wp += 64 * 4;
  float*    Zp   = (float*)wp;             wp += 256 * 4;
  unsigned* cnt  = (unsigned*)wp;          wp += 64 * 4;
  unsigned* kef  = (unsigned*)wp;          wp += 64 * 4;
  unsigned* hist = (unsigned*)wp;          wp += 64 * 32 * 4;
  float*    tv   = (float*)wp;             wp += 64 * 64 * 4;
  unsigned* ti   = (unsigned*)wp;          wp += 64 * 64 * 4;
  float*    cval = (float*)wp;             wp += (size_t)64 * CAND_CAP * 4;
  unsigned* cidx = (unsigned*)wp;          wp += (size_t)64 * CAND_CAP * 4;

  hipLaunchKernelGGL(Sampler_gather,   dim3((B_ * D_ + 255) / 256), dim3(256), 0, stream, x, out_pos, hhi, hlo, cnt, Mo, hist);
  hipLaunchKernelGGL(Sampler_gemm,     dim3(V_ / 256), dim3(256), 0, stream, hhi, hlo, emb, ebias, logits);
  hipLaunchKernelGGL(Sampler_rowmax,   dim3(256), dim3(256), 0, stream, logits, Mo);
  hipLaunchKernelGGL(Sampler_zcount,   dim3(256), dim3(256), 0, stream, logits, Mo, Mb, Zp, hist);
  hipLaunchKernelGGL(Sampler_thresh,   dim3(1), dim3(64), 0, stream, hist, Mb, Tb);
  hipLaunchKernelGGL(Sampler_collect,  dim3(256), dim3(256), 0, stream, logits, Tb, cnt, cval, cidx);
  hipLaunchKernelGGL(Sampler_topk,     dim3(64), dim3(256), 0, stream, cnt, cval, cidx, top_ks, tv, ti, kef);
  hipLaunchKernelGGL(Sampler_sample,   dim3(64), dim3(64), 0, stream, tv, ti, kef, Mb, Zp, top_ps, out);
}